// Round 3
// baseline (195.926 us; speedup 1.0000x reference)
//
#include <hip/hip_runtime.h>

// ws layout (floats):
//   [0, 256)              mean partial sums [b][ch]
//   [256, 16640)          wmx[16 p][64 ch][16] = {wc_mixed[8], we_mixed[8]}
//   [16640, 2113792)      yrec[16 p][256 i][64 ch][8] =
//                         {rb0(int), rb1(int), wy0*wx0, wy0*wx1, wy1*wx0, wy1*wx1, 0, 0}
//                         rb* = ch*4752 + (yclamp+1)*72 + 4 + bx  (index into xpad plane)
//   [2113792, 3330304)    xpad[4 b][64 ch][66][72]  zero-padded copy of x
//                         (rows -1..64 -> 0..65, cols -4..67 -> 0..71)

__device__ __forceinline__ float relu_(float v){ return fmaxf(v, 0.f); }
__device__ __forceinline__ float sigm_(float v){ return 1.f/(1.f + __expf(-v)); }

__global__ void k_mean(const float* __restrict__ x, float* __restrict__ ws) {
  const int ch = blockIdx.x, b = blockIdx.y, t = threadIdx.x;
  const float* xp = x + (size_t)(b*64 + ch)*4096;
  const float4* p4 = reinterpret_cast<const float4*>(xp);
  float4 v0 = p4[t], v1 = p4[t+256], v2 = p4[t+512], v3 = p4[t+768];
  float s = ((v0.x+v0.y)+(v0.z+v0.w)) + ((v1.x+v1.y)+(v1.z+v1.w))
          + ((v2.x+v2.y)+(v2.z+v2.w)) + ((v3.x+v3.y)+(v3.z+v3.w));
  __shared__ float red[256];
  red[t] = s; __syncthreads();
  for (int off = 128; off > 0; off >>= 1) {
    if (t < off) red[t] += red[t + off];
    __syncthreads();
  }
  if (t == 0) ws[b*64 + ch] = red[0];

  // zero-padded copy: plane [66 rows][72 cols], interior at [1..64][4..67]
  float* dst = ws + 2113792 + (size_t)(b*64 + ch)*4752;
  if (t < 66) {
    float4* drow = reinterpret_cast<float4*>(dst + t*72);
    const float4 z = make_float4(0.f, 0.f, 0.f, 0.f);
    if (t == 0 || t == 65) {
      #pragma unroll
      for (int q = 0; q < 18; ++q) drow[q] = z;
    } else {
      const float4* srow = reinterpret_cast<const float4*>(xp + (t-1)*64);
      drow[0] = z;
      #pragma unroll
      for (int q = 0; q < 16; ++q) drow[1+q] = srow[q];
      drow[17] = z;
    }
  }
}

__launch_bounds__(256)
__global__ void k_phase(const float* __restrict__ wc, const float* __restrict__ we,
    const float* __restrict__ Wb1, const float* __restrict__ bb1,
    const float* __restrict__ Wb2, const float* __restrict__ bb2,
    const float* __restrict__ Wr1, const float* __restrict__ br1,
    const float* __restrict__ Wr2, const float* __restrict__ br2,
    const float* __restrict__ Wq1, const float* __restrict__ bq1,
    const float* __restrict__ Wq2, const float* __restrict__ bq2,
    const float* __restrict__ Wq3, const float* __restrict__ bq3,
    const float* __restrict__ Wo1, const float* __restrict__ bo1,
    const float* __restrict__ Wo2, const float* __restrict__ bo2,
    const float* __restrict__ Wo3, const float* __restrict__ bo3,
    float* __restrict__ ws)
{
  const int p = blockIdx.x, pi = p >> 2, pj = p & 3;
  const int t = threadIdx.x;
  const float chv = 0.25f*pi - 0.375f, cwv = 0.25f*pj - 0.375f;

  // Natural-orientation staging, leading dim padded 64->66: matvec reads
  // W[t*66+c] hit banks (2t+c)%32 -> 2-way aliasing, which is free (m136).
  __shared__ float WbL1[64*66];
  __shared__ float WbL2[64*66];
  __shared__ float WrL1[64*66];
  __shared__ float WqL2[64*66];
  __shared__ __align__(16) float Wo2L[4096];
  __shared__ __align__(16) float Wo1L[256];
  __shared__ __align__(16) float wcL[2048];
  __shared__ __align__(16) float weL[2048];
  __shared__ float Wo3L[128];
  __shared__ float Wq1L[256], Wq3L[256];
  __shared__ float Wr2L[64];
  __shared__ float bb1L[64], bb2L[64], br1L[64], bq1L[64], bq2L[64];
  __shared__ float bo1L[64], bo2L[64];

  __shared__ float meanL[64];
  __shared__ __align__(16) float t1L[64][4];
  __shared__ __align__(16) float embL[64][4];
  __shared__ __align__(16) float rpL[64][4];
  __shared__ float r4[4];
  __shared__ float q1L[64], q2L[64];
  __shared__ float rwL[4];
  __shared__ float oxL[64][4], oyL[64][4];
  __shared__ float oxF[64], oyF[64];

  // ---- stage EVERYTHING into LDS upfront (coalesced; overlapped latency) ----
  {
    const float* srcs[4] = {Wb1, Wb2, Wr1, Wq2};
    float* dsts[4] = {WbL1, WbL2, WrL1, WqL2};
    for (int m = 0; m < 4; ++m) {
      const float4* W4 = reinterpret_cast<const float4*>(srcs[m]);
      float* WL = dsts[m];
      for (int v = t; v < 1024; v += 256) {
        float4 d = W4[v];
        const int r = v >> 4, c = (v & 15) << 2;
        float* q = &WL[r*66 + c];
        q[0] = d.x; q[1] = d.y; q[2] = d.z; q[3] = d.w;
      }
    }
    for (int v = t; v < 1024; v += 256)
      reinterpret_cast<float4*>(Wo2L)[v] = reinterpret_cast<const float4*>(Wo2)[v];
    for (int v = t; v < 512; v += 256) {
      reinterpret_cast<float4*>(wcL)[v] = reinterpret_cast<const float4*>(wc)[v];
      reinterpret_cast<float4*>(weL)[v] = reinterpret_cast<const float4*>(we)[v];
    }
    if (t < 64) {
      reinterpret_cast<float4*>(Wo1L)[t] = reinterpret_cast<const float4*>(Wo1)[t];
      reinterpret_cast<float4*>(Wq1L)[t] = reinterpret_cast<const float4*>(Wq1)[t];
      reinterpret_cast<float4*>(Wq3L)[t] = reinterpret_cast<const float4*>(Wq3)[t];
      bb1L[t] = bb1[t]; bb2L[t] = bb2[t]; br1L[t] = br1[t];
      bq1L[t] = bq1[t]; bq2L[t] = bq2[t];
      bo1L[t] = bo1[t]; bo2L[t] = bo2[t];
      Wr2L[t] = Wr2[t];
      const float* wsp = ws;
      meanL[t] = (wsp[t] + wsp[64+t] + wsp[128+t] + wsp[192+t]) * (1.f/16384.f);
    }
    if (t >= 64 && t < 192) Wo3L[t-64] = Wo3[t-64];
  }
  __syncthreads();

  if (t < 64) {  // body layer 1 (f=1..3 analytic: inp features uniform)
    float a0 = 0.f, as = 0.f;
    const float* row = &WbL1[t*66];
    #pragma unroll 8
    for (int c = 0; c < 64; ++c) { float w = row[c]; a0 += w*meanL[c]; as += w; }
    float bb = bb1L[t];
    t1L[t][0] = relu_(a0 + bb);
    t1L[t][1] = relu_(0.25f*as + bb);
    t1L[t][2] = relu_(chv*as + bb);
    t1L[t][3] = relu_(cwv*as + bb);
  }
  __syncthreads();
  if (t < 64) {  // body layer 2
    float bb = bb2L[t];
    float e0=bb,e1=bb,e2=bb,e3=bb;
    const float* row = &WbL2[t*66];
    #pragma unroll 8
    for (int c = 0; c < 64; ++c) {
      float w = row[c];
      float4 tv = *reinterpret_cast<const float4*>(&t1L[c][0]);
      e0 += w*tv.x; e1 += w*tv.y; e2 += w*tv.z; e3 += w*tv.w;
    }
    embL[t][0]=relu_(e0); embL[t][1]=relu_(e1); embL[t][2]=relu_(e2); embL[t][3]=relu_(e3);
  }
  __syncthreads();
  if (t < 64) {  // routing_1 layer 1
    float bb = br1L[t];
    float p0=bb,p1=bb,p2=bb,p3=bb;
    const float* row = &WrL1[t*66];
    #pragma unroll 8
    for (int c = 0; c < 64; ++c) {
      float w = row[c];
      float4 ev = *reinterpret_cast<const float4*>(&embL[c][0]);
      p0 += w*ev.x; p1 += w*ev.y; p2 += w*ev.z; p3 += w*ev.w;
    }
    rpL[t][0]=relu_(p0); rpL[t][1]=relu_(p1); rpL[t][2]=relu_(p2); rpL[t][3]=relu_(p3);
  }
  __syncthreads();
  if (t < 4) {   // routing_1 layer 2 + sigmoid
    float acc = br2[0];
    #pragma unroll 8
    for (int c = 0; c < 64; ++c) acc += Wr2L[c]*rpL[c][t];
    r4[t] = sigm_(acc);
  }
  __syncthreads();
  if (t < 64) {  // routing_2 layer 1
    float acc = bq1L[t];
    #pragma unroll
    for (int f = 0; f < 4; ++f) acc += Wq1L[t*4+f]*r4[f];
    q1L[t] = relu_(acc);
  }
  __syncthreads();
  if (t < 64) {  // routing_2 layer 2
    float acc = bq2L[t];
    const float* row = &WqL2[t*66];
    #pragma unroll 8
    for (int c = 0; c < 64; ++c) acc += row[c]*q1L[c];
    q2L[t] = relu_(acc);
  }
  __syncthreads();
  if (t < 4) {   // routing_2 layer 3 + sigmoid -> expert weights
    float acc = bq3[t];
    #pragma unroll 8
    for (int c = 0; c < 64; ++c) acc += Wq3L[t*64+c]*q2L[c];
    rwL[t] = sigm_(acc);
  }
  __syncthreads();

  // offset head: ch = lane (t&63), quarter q = wave index (t>>6) -> all Wo2/Wo1
  // row addresses are wave-uniform -> LDS broadcast, conflict-free.
  {
    const int ch = t & 63, q = t >> 6;
    const float4 e = *reinterpret_cast<const float4*>(&embL[ch][0]);
    float v1[64];
    #pragma unroll
    for (int o = 0; o < 64; ++o) {
      float4 w = *reinterpret_cast<const float4*>(&Wo1L[o*4]);
      v1[o] = relu_(w.x*e.x + w.y*e.y + w.z*e.z + w.w*e.w + bo1L[o]);
    }
    float ox = 0.f, oy = 0.f;
    for (int o = q*16; o < q*16+16; ++o) {
      float acc = bo2L[o];
      const float4* row = reinterpret_cast<const float4*>(&Wo2L[o*64]);
      #pragma unroll
      for (int k = 0; k < 16; ++k) {
        float4 w = row[k];
        acc += w.x*v1[4*k+0] + w.y*v1[4*k+1] + w.z*v1[4*k+2] + w.w*v1[4*k+3];
      }
      acc = relu_(acc);
      ox += Wo3L[o]*acc;
      oy += Wo3L[64+o]*acc;
    }
    oxL[ch][q] = ox; oyL[ch][q] = oy;
  }
  __syncthreads();
  if (t < 64) {
    oxF[t] = oxL[t][0]+oxL[t][1]+oxL[t][2]+oxL[t][3] + bo3[0];
    oyF[t] = oyL[t][0]+oyL[t][1]+oyL[t][2]+oyL[t][3] + bo3[1];
  }
  __syncthreads();

  // wmx[p][ch][16] = {sum_e r_e wc[e][k][ch] (k=0..7), sum_e r_e we[e][ch][k] (k=0..7)}
  {
    const float r0 = rwL[0], r1 = rwL[1], r2 = rwL[2], r3 = rwL[3];
    for (int idx = t; idx < 1024; idx += 256) {
      const int ch = idx >> 4, k = idx & 15;
      float v;
      if (k < 8) {
        v = r0*wcL[(0*8+k)*64+ch] + r1*wcL[(1*8+k)*64+ch]
          + r2*wcL[(2*8+k)*64+ch] + r3*wcL[(3*8+k)*64+ch];
      } else {
        const int kk = k - 8;
        v = r0*weL[(0*64+ch)*8+kk] + r1*weL[(1*64+ch)*8+kk]
          + r2*weL[(2*64+ch)*8+kk] + r3*weL[(3*64+ch)*8+kk];
      }
      ws[256 + (p*64+ch)*16 + k] = v;
    }
  }

  // yrec[p][i][ch][8]: fused bilinear record. With j = 4*lane + pj:
  //   px = lane + B, B = pj*0.25-0.375+ox  ->  wx uniform per (p,ch),
  // fold wx into wy: fv = w00*g00 + w01*g01 + w10*g10 + w11*g11.
  // Row bases point into zero-padded xpad; y-validity masks in the weights.
  {
    const int ch = t & 63, iq = t >> 6;
    const float oy = oyF[ch];
    const float B = 0.25f*pj - 0.375f + oxF[ch];
    const float bxf = floorf(B);
    const float wx = B - bxf;
    const float wx0 = 1.f - wx, wx1 = wx;
    const int bx = min(max((int)bxf, -4), 3);   // pad coverage; actual |ox| << 1
    const int chbase = ch*4752 + 4 + bx;
    float4* dst = reinterpret_cast<float4*>(ws + 16640 + (size_t)p*131072);
    for (int n = 0; n < 64; ++n) {
      const int i = iq*64 + n;
      const float py = i*0.25f - 0.375f + oy;
      const float fy = floorf(py);
      const float wy = py - fy;
      const int y0 = (int)fy, y1 = y0 + 1;
      const int y0c = min(max(y0, -1), 64), y1c = min(max(y1, -1), 64);
      const float wy0 = ((unsigned)y0 <= 63u) ? (1.f - wy) : 0.f;
      const float wy1 = ((unsigned)y1 <= 63u) ? wy : 0.f;
      float4 A, Bq;
      A.x = __int_as_float(chbase + (y0c+1)*72);
      A.y = __int_as_float(chbase + (y1c+1)*72);
      A.z = wy0*wx0; A.w = wy0*wx1;
      Bq.x = wy1*wx0; Bq.y = wy1*wx1; Bq.z = 0.f; Bq.w = 0.f;
      dst[(i*64 + ch)*2 + 0] = A;
      dst[(i*64 + ch)*2 + 1] = Bq;
    }
  }
}

// j = 4*lane + wave: all per-channel coefficients wave-uniform -> SGPR s_loads;
// gathers lane-coalesced from zero-padded xpad (no clamps/masks/addr VALU);
// epilogue transposes through LDS so global stores are contiguous.
// (256,3): ~170 VGPR budget so fea[64]+mid[8]+temps stay in registers WITHOUT
// spilling — rounds 1-2 used (256,4) and the compiler spilled fea to scratch
// (VGPR_Count 44-48 with a 64-element live array = spill), costing ~128MB of
// hidden scratch traffic.
__launch_bounds__(256, 3)
__global__ void k_main(const float* __restrict__ ws, float* __restrict__ out) {
  const int i = blockIdx.x;   // output row 0..255
  const int b = blockIdx.y;   // batch 0..3
  const int w = __builtin_amdgcn_readfirstlane((int)(threadIdx.x >> 6)); // = pj
  const int l = threadIdx.x & 63;
  const int p = (i & 3)*4 + w;

  const float* __restrict__ wmx = ws + 256 + p*1024;                       // [ch][16]
  const float* __restrict__ yr  = ws + 16640 + (size_t)p*131072 + (size_t)i*512; // [ch][8]
  const float* __restrict__ xpb = ws + 2113792 + (size_t)b*304128;

  __shared__ float tile[4096];   // [16 cc][4 w][64 l], xor-swizzled -> 2-way max

  float fea[64];
  float m0=0.f,m1=0.f,m2=0.f,m3=0.f,m4=0.f,m5=0.f,m6=0.f,m7=0.f;

  #pragma unroll
  for (int ch = 0; ch < 64; ++ch) {
    const float4 ra = *reinterpret_cast<const float4*>(yr + ch*8);
    const float4 rb = *reinterpret_cast<const float4*>(yr + ch*8 + 4);
    const float4 wa = *reinterpret_cast<const float4*>(wmx + ch*16);
    const float4 wb = *reinterpret_cast<const float4*>(wmx + ch*16 + 4);
    const int r0 = __float_as_int(ra.x), r1 = __float_as_int(ra.y);
    const float g00 = xpb[r0 + l], g01 = xpb[r0 + l + 1];
    const float g10 = xpb[r1 + l], g11 = xpb[r1 + l + 1];
    const float fv = g00*ra.z + g01*ra.w + g10*rb.x + g11*rb.y;
    fea[ch] = fv;
    m0 += wa.x*fv; m1 += wa.y*fv; m2 += wa.z*fv; m3 += wa.w*fv;
    m4 += wb.x*fv; m5 += wb.y*fv; m6 += wb.z*fv; m7 += wb.w*fv;
  }

  float* __restrict__ ob = out + (size_t)b*4194304 + i*256;
  const int sw = (w & 1) << 4;
  #pragma unroll
  for (int c4 = 0; c4 < 4; ++c4) {
    #pragma unroll
    for (int cc = 0; cc < 16; ++cc) {
      const int ch = c4*16 + cc;
      const float4 wa = *reinterpret_cast<const float4*>(wmx + ch*16 + 8);
      const float4 wb = *reinterpret_cast<const float4*>(wmx + ch*16 + 12);
      float acc = fea[ch];
      acc += wa.x*m0 + wa.y*m1 + wa.z*m2 + wa.w*m3;
      acc += wb.x*m4 + wb.y*m5 + wb.z*m6 + wb.w*m7;
      tile[cc*256 + w*64 + (l ^ sw)] = acc;   // value for j = 4*l + w
    }
    __syncthreads();
    #pragma unroll
    for (int cc = 0; cc < 16; ++cc) {
      const int ch = c4*16 + cc;
      // thread (w,l) stores j = w*64 + l  <-  slot (w_src=l&3, l_src=w*16+(l>>2))
      const float v = tile[cc*256 + (l&3)*64 + ((w*16 + (l>>2)) ^ ((l&1)<<4))];
      ob[ch*65536 + w*64 + l] = v;
    }
    __syncthreads();
  }
}

extern "C" void kernel_launch(void* const* d_in, const int* in_sizes, int n_in,
                              void* d_out, int out_size, void* d_ws, size_t ws_size,
                              hipStream_t stream) {
  const float* x   = (const float*)d_in[0];
  const float* wc  = (const float*)d_in[1];
  const float* we  = (const float*)d_in[2];
  const float* Wb1 = (const float*)d_in[3];
  const float* bb1 = (const float*)d_in[4];
  const float* Wb2 = (const float*)d_in[5];
  const float* bb2 = (const float*)d_in[6];
  const float* Wr1 = (const float*)d_in[7];
  const float* br1 = (const float*)d_in[8];
  const float* Wr2 = (const float*)d_in[9];
  const float* br2 = (const float*)d_in[10];
  const float* Wq1 = (const float*)d_in[11];
  const float* bq1 = (const float*)d_in[12];
  const float* Wq2 = (const float*)d_in[13];
  const float* bq2 = (const float*)d_in[14];
  const float* Wq3 = (const float*)d_in[15];
  const float* bq3 = (const float*)d_in[16];
  const float* Wo1 = (const float*)d_in[17];
  const float* bo1 = (const float*)d_in[18];
  const float* Wo2 = (const float*)d_in[19];
  const float* bo2 = (const float*)d_in[20];
  const float* Wo3 = (const float*)d_in[21];
  const float* bo3 = (const float*)d_in[22];
  float* ws  = (float*)d_ws;
  float* out = (float*)d_out;

  k_mean<<<dim3(64, 4), 256, 0, stream>>>(x, ws);
  k_phase<<<16, 256, 0, stream>>>(wc, we, Wb1, bb1, Wb2, bb2, Wr1, br1, Wr2, br2,
                                  Wq1, bq1, Wq2, bq2, Wq3, bq3,
                                  Wo1, bo1, Wo2, bo2, Wo3, bo3, ws);
  k_main<<<dim3(256, 4), 256, 0, stream>>>(ws, out);
}

// Round 4
// 168.184 us; speedup vs baseline: 1.1649x; 1.1649x over previous
//
#include <hip/hip_runtime.h>

// ws layout (floats):
//   [0, 256)            mean partial sums [b][ch]
//   [256, 16640)        wmx[16 p][64 ch][16] = {wc_mixed[8], we_mixed[8]}
//   [16640, 20736)      pcf[16 p][64 ch][4]  = {chbase(int bits), wx0, wx1, oy}
//                       chbase = ch*4752 + 4 + bx   (index into xpad plane)
//   [20736, 1237248)    xpad[4 b][64 ch][66][72]  zero-padded copy of x
//                       (rows -1..64 -> 0..65, cols -4..67 -> 0..71)

__device__ __forceinline__ float relu_(float v){ return fmaxf(v, 0.f); }
__device__ __forceinline__ float sigm_(float v){ return 1.f/(1.f + __expf(-v)); }

__global__ void k_mean(const float* __restrict__ x, float* __restrict__ ws) {
  const int ch = blockIdx.x, b = blockIdx.y, t = threadIdx.x;
  const float* xp = x + (size_t)(b*64 + ch)*4096;
  const float4* p4 = reinterpret_cast<const float4*>(xp);
  float4 v0 = p4[t], v1 = p4[t+256], v2 = p4[t+512], v3 = p4[t+768];
  float s = ((v0.x+v0.y)+(v0.z+v0.w)) + ((v1.x+v1.y)+(v1.z+v1.w))
          + ((v2.x+v2.y)+(v2.z+v2.w)) + ((v3.x+v3.y)+(v3.z+v3.w));
  __shared__ float red[256];
  red[t] = s; __syncthreads();
  for (int off = 128; off > 0; off >>= 1) {
    if (t < off) red[t] += red[t + off];
    __syncthreads();
  }
  if (t == 0) ws[b*64 + ch] = red[0];

  // zero-padded copy: plane [66 rows][72 cols], interior at [1..64][4..67]
  float* dst = ws + 20736 + (size_t)(b*64 + ch)*4752;
  if (t < 66) {
    float4* drow = reinterpret_cast<float4*>(dst + t*72);
    const float4 z = make_float4(0.f, 0.f, 0.f, 0.f);
    if (t == 0 || t == 65) {
      #pragma unroll
      for (int q = 0; q < 18; ++q) drow[q] = z;
    } else {
      const float4* srow = reinterpret_cast<const float4*>(xp + (t-1)*64);
      drow[0] = z;
      #pragma unroll
      for (int q = 0; q < 16; ++q) drow[1+q] = srow[q];
      drow[17] = z;
    }
  }
}

__launch_bounds__(256)
__global__ void k_phase(const float* __restrict__ wc, const float* __restrict__ we,
    const float* __restrict__ Wb1, const float* __restrict__ bb1,
    const float* __restrict__ Wb2, const float* __restrict__ bb2,
    const float* __restrict__ Wr1, const float* __restrict__ br1,
    const float* __restrict__ Wr2, const float* __restrict__ br2,
    const float* __restrict__ Wq1, const float* __restrict__ bq1,
    const float* __restrict__ Wq2, const float* __restrict__ bq2,
    const float* __restrict__ Wq3, const float* __restrict__ bq3,
    const float* __restrict__ Wo1, const float* __restrict__ bo1,
    const float* __restrict__ Wo2, const float* __restrict__ bo2,
    const float* __restrict__ Wo3, const float* __restrict__ bo3,
    float* __restrict__ ws)
{
  const int p = blockIdx.x, pi = p >> 2, pj = p & 3;
  const int t = threadIdx.x;
  const float chv = 0.25f*pi - 0.375f, cwv = 0.25f*pj - 0.375f;

  // Natural-orientation staging, leading dim padded 64->66: matvec reads
  // W[t*66+c] hit banks (2t+c)%32 -> 2-way aliasing, which is free (m136).
  __shared__ float WbL1[64*66];
  __shared__ float WbL2[64*66];
  __shared__ float WrL1[64*66];
  __shared__ float WqL2[64*66];
  __shared__ __align__(16) float Wo2L[4096];
  __shared__ __align__(16) float Wo1L[256];
  __shared__ __align__(16) float wcL[2048];
  __shared__ __align__(16) float weL[2048];
  __shared__ float Wo3L[128];
  __shared__ float Wq1L[256], Wq3L[256];
  __shared__ float Wr2L[64];
  __shared__ float bb1L[64], bb2L[64], br1L[64], bq1L[64], bq2L[64];
  __shared__ float bo1L[64], bo2L[64];

  __shared__ float meanL[64];
  __shared__ __align__(16) float t1L[64][4];
  __shared__ __align__(16) float embL[64][4];
  __shared__ __align__(16) float rpL[64][4];
  __shared__ float r4[4];
  __shared__ float q1L[64], q2L[64];
  __shared__ float rwL[4];
  __shared__ float oxL[64][4], oyL[64][4];
  __shared__ float oxF[64], oyF[64];

  // ---- stage EVERYTHING into LDS upfront (coalesced; overlapped latency) ----
  {
    const float* srcs[4] = {Wb1, Wb2, Wr1, Wq2};
    float* dsts[4] = {WbL1, WbL2, WrL1, WqL2};
    for (int m = 0; m < 4; ++m) {
      const float4* W4 = reinterpret_cast<const float4*>(srcs[m]);
      float* WL = dsts[m];
      for (int v = t; v < 1024; v += 256) {
        float4 d = W4[v];
        const int r = v >> 4, c = (v & 15) << 2;
        float* q = &WL[r*66 + c];
        q[0] = d.x; q[1] = d.y; q[2] = d.z; q[3] = d.w;
      }
    }
    for (int v = t; v < 1024; v += 256)
      reinterpret_cast<float4*>(Wo2L)[v] = reinterpret_cast<const float4*>(Wo2)[v];
    for (int v = t; v < 512; v += 256) {
      reinterpret_cast<float4*>(wcL)[v] = reinterpret_cast<const float4*>(wc)[v];
      reinterpret_cast<float4*>(weL)[v] = reinterpret_cast<const float4*>(we)[v];
    }
    if (t < 64) {
      reinterpret_cast<float4*>(Wo1L)[t] = reinterpret_cast<const float4*>(Wo1)[t];
      reinterpret_cast<float4*>(Wq1L)[t] = reinterpret_cast<const float4*>(Wq1)[t];
      reinterpret_cast<float4*>(Wq3L)[t] = reinterpret_cast<const float4*>(Wq3)[t];
      bb1L[t] = bb1[t]; bb2L[t] = bb2[t]; br1L[t] = br1[t];
      bq1L[t] = bq1[t]; bq2L[t] = bq2[t];
      bo1L[t] = bo1[t]; bo2L[t] = bo2[t];
      Wr2L[t] = Wr2[t];
      const float* wsp = ws;
      meanL[t] = (wsp[t] + wsp[64+t] + wsp[128+t] + wsp[192+t]) * (1.f/16384.f);
    }
    if (t >= 64 && t < 192) Wo3L[t-64] = Wo3[t-64];
  }
  __syncthreads();

  if (t < 64) {  // body layer 1 (f=1..3 analytic: inp features uniform)
    float a0 = 0.f, as = 0.f;
    const float* row = &WbL1[t*66];
    #pragma unroll 8
    for (int c = 0; c < 64; ++c) { float w = row[c]; a0 += w*meanL[c]; as += w; }
    float bb = bb1L[t];
    t1L[t][0] = relu_(a0 + bb);
    t1L[t][1] = relu_(0.25f*as + bb);
    t1L[t][2] = relu_(chv*as + bb);
    t1L[t][3] = relu_(cwv*as + bb);
  }
  __syncthreads();
  if (t < 64) {  // body layer 2
    float bb = bb2L[t];
    float e0=bb,e1=bb,e2=bb,e3=bb;
    const float* row = &WbL2[t*66];
    #pragma unroll 8
    for (int c = 0; c < 64; ++c) {
      float w = row[c];
      float4 tv = *reinterpret_cast<const float4*>(&t1L[c][0]);
      e0 += w*tv.x; e1 += w*tv.y; e2 += w*tv.z; e3 += w*tv.w;
    }
    embL[t][0]=relu_(e0); embL[t][1]=relu_(e1); embL[t][2]=relu_(e2); embL[t][3]=relu_(e3);
  }
  __syncthreads();
  if (t < 64) {  // routing_1 layer 1
    float bb = br1L[t];
    float p0=bb,p1=bb,p2=bb,p3=bb;
    const float* row = &WrL1[t*66];
    #pragma unroll 8
    for (int c = 0; c < 64; ++c) {
      float w = row[c];
      float4 ev = *reinterpret_cast<const float4*>(&embL[c][0]);
      p0 += w*ev.x; p1 += w*ev.y; p2 += w*ev.z; p3 += w*ev.w;
    }
    rpL[t][0]=relu_(p0); rpL[t][1]=relu_(p1); rpL[t][2]=relu_(p2); rpL[t][3]=relu_(p3);
  }
  __syncthreads();
  if (t < 4) {   // routing_1 layer 2 + sigmoid
    float acc = br2[0];
    #pragma unroll 8
    for (int c = 0; c < 64; ++c) acc += Wr2L[c]*rpL[c][t];
    r4[t] = sigm_(acc);
  }
  __syncthreads();
  if (t < 64) {  // routing_2 layer 1
    float acc = bq1L[t];
    #pragma unroll
    for (int f = 0; f < 4; ++f) acc += Wq1L[t*4+f]*r4[f];
    q1L[t] = relu_(acc);
  }
  __syncthreads();
  if (t < 64) {  // routing_2 layer 2
    float acc = bq2L[t];
    const float* row = &WqL2[t*66];
    #pragma unroll 8
    for (int c = 0; c < 64; ++c) acc += row[c]*q1L[c];
    q2L[t] = relu_(acc);
  }
  __syncthreads();
  if (t < 4) {   // routing_2 layer 3 + sigmoid -> expert weights
    float acc = bq3[t];
    #pragma unroll 8
    for (int c = 0; c < 64; ++c) acc += Wq3L[t*64+c]*q2L[c];
    rwL[t] = sigm_(acc);
  }
  __syncthreads();

  // offset head: ch = lane (t&63), quarter q = wave index (t>>6) -> all Wo2/Wo1
  // row addresses are wave-uniform -> LDS broadcast, conflict-free.
  {
    const int ch = t & 63, q = t >> 6;
    const float4 e = *reinterpret_cast<const float4*>(&embL[ch][0]);
    float v1[64];
    #pragma unroll
    for (int o = 0; o < 64; ++o) {
      float4 w = *reinterpret_cast<const float4*>(&Wo1L[o*4]);
      v1[o] = relu_(w.x*e.x + w.y*e.y + w.z*e.z + w.w*e.w + bo1L[o]);
    }
    float ox = 0.f, oy = 0.f;
    for (int o = q*16; o < q*16+16; ++o) {
      float acc = bo2L[o];
      const float4* row = reinterpret_cast<const float4*>(&Wo2L[o*64]);
      #pragma unroll
      for (int k = 0; k < 16; ++k) {
        float4 w = row[k];
        acc += w.x*v1[4*k+0] + w.y*v1[4*k+1] + w.z*v1[4*k+2] + w.w*v1[4*k+3];
      }
      acc = relu_(acc);
      ox += Wo3L[o]*acc;
      oy += Wo3L[64+o]*acc;
    }
    oxL[ch][q] = ox; oyL[ch][q] = oy;
  }
  __syncthreads();
  if (t < 64) {
    oxF[t] = oxL[t][0]+oxL[t][1]+oxL[t][2]+oxL[t][3] + bo3[0];
    oyF[t] = oyL[t][0]+oyL[t][1]+oyL[t][2]+oyL[t][3] + bo3[1];
  }
  __syncthreads();

  // wmx[p][ch][16] = {sum_e r_e wc[e][k][ch] (k=0..7), sum_e r_e we[e][ch][k] (k=0..7)}
  {
    const float r0 = rwL[0], r1 = rwL[1], r2 = rwL[2], r3 = rwL[3];
    for (int idx = t; idx < 1024; idx += 256) {
      const int ch = idx >> 4, k = idx & 15;
      float v;
      if (k < 8) {
        v = r0*wcL[(0*8+k)*64+ch] + r1*wcL[(1*8+k)*64+ch]
          + r2*wcL[(2*8+k)*64+ch] + r3*wcL[(3*8+k)*64+ch];
      } else {
        const int kk = k - 8;
        v = r0*weL[(0*64+ch)*8+kk] + r1*weL[(1*64+ch)*8+kk]
          + r2*weL[(2*64+ch)*8+kk] + r3*weL[(3*64+ch)*8+kk];
      }
      ws[256 + (p*64+ch)*16 + k] = v;
    }
  }

  // pcf[p][ch] = {chbase, wx0, wx1, oy}: with j = 4*lane + pj, px = lane + B,
  // B = pj*0.25-0.375+ox -> wx wave-uniform, bx folded into the xpad base.
  // k_main recomputes the y-side per (i,ch) on the fly (cheap VALU) instead of
  // streaming a 8MB HBM-cold record table (round-3 lesson: latency-bound).
  if (t < 64) {
    const float B = 0.25f*pj - 0.375f + oxF[t];
    const float bxf = floorf(B);
    const float wx = B - bxf;
    const int bx = min(max((int)bxf, -4), 3);   // pad coverage; actual |ox| << 1
    float4 r;
    r.x = __int_as_float(t*4752 + 4 + bx);
    r.y = 1.f - wx;
    r.z = wx;
    r.w = oyF[t];
    *reinterpret_cast<float4*>(ws + 16640 + (p*64 + t)*4) = r;
  }
}

// j = 4*lane + wave: per-channel coefficients wave-uniform, staged once per
// block into LDS (coalesced) and read back as broadcasts (conflict-free).
// Gathers lane-coalesced from zero-padded xpad; y-side bilinear state
// recomputed in-loop (~10 VALU/ch, all wave-uniform). Epilogue transposes
// through LDS so global stores are contiguous. (256,4): full grid co-resident.
__launch_bounds__(256, 4)
__global__ void k_main(const float* __restrict__ ws, float* __restrict__ out) {
  const int i = blockIdx.x;   // output row 0..255
  const int b = blockIdx.y;   // batch 0..3
  const int w = __builtin_amdgcn_readfirstlane((int)(threadIdx.x >> 6)); // = pj
  const int l = threadIdx.x & 63;
  const int t = threadIdx.x;
  const int pi4 = (i & 3)*4;  // block's 4 waves use p = pi4 + w

  const float* __restrict__ xpb = ws + 20736 + (size_t)b*304128;

  __shared__ __align__(16) float wmxL[4096];  // [4 w][64 ch][16]
  __shared__ __align__(16) float pcfL[1024];  // [4 w][64 ch][4]
  __shared__ float tile[4096];                // [16 cc][4 w][64 l], xor-swizzled

  {
    const float4* s1 = reinterpret_cast<const float4*>(ws + 256 + pi4*1024);
    float4* d1 = reinterpret_cast<float4*>(wmxL);
    d1[t] = s1[t];
    d1[t+256] = s1[t+256];
    d1[t+512] = s1[t+512];
    d1[t+768] = s1[t+768];
    const float4* s2 = reinterpret_cast<const float4*>(ws + 16640 + pi4*256);
    reinterpret_cast<float4*>(pcfL)[t] = s2[t];
  }
  __syncthreads();

  const float* __restrict__ wmxw = &wmxL[w*1024];
  const float* __restrict__ pcfw = &pcfL[w*256];
  const float fi = i*0.25f - 0.375f;

  float fea[64];
  float m0=0.f,m1=0.f,m2=0.f,m3=0.f,m4=0.f,m5=0.f,m6=0.f,m7=0.f;

  #pragma unroll
  for (int ch = 0; ch < 64; ++ch) {
    const float4 c = *reinterpret_cast<const float4*>(pcfw + ch*4);   // broadcast
    const float4 wa = *reinterpret_cast<const float4*>(wmxw + ch*16);
    const float4 wb = *reinterpret_cast<const float4*>(wmxw + ch*16 + 4);
    const int base = __float_as_int(c.x);
    const float wx0 = c.y, wx1 = c.z;
    // y-side (wave-uniform, recomputed: ~10 VALU)
    const float py = fi + c.w;
    const float fy = floorf(py);
    const float wy = py - fy;
    const int y0 = (int)fy, y1 = y0 + 1;
    const int y0c = min(max(y0, -1), 64), y1c = min(max(y1, -1), 64);
    const float wy0 = ((unsigned)y0 <= 63u) ? (1.f - wy) : 0.f;
    const float wy1 = ((unsigned)y1 <= 63u) ? wy : 0.f;
    const int r0 = base + (y0c+1)*72, r1 = base + (y1c+1)*72;
    const float a0 = wy0*wx0, a1 = wy0*wx1, a2 = wy1*wx0, a3 = wy1*wx1;
    const float g00 = xpb[r0 + l], g01 = xpb[r0 + l + 1];
    const float g10 = xpb[r1 + l], g11 = xpb[r1 + l + 1];
    const float fv = g00*a0 + g01*a1 + g10*a2 + g11*a3;
    fea[ch] = fv;
    m0 += wa.x*fv; m1 += wa.y*fv; m2 += wa.z*fv; m3 += wa.w*fv;
    m4 += wb.x*fv; m5 += wb.y*fv; m6 += wb.z*fv; m7 += wb.w*fv;
  }

  float* __restrict__ ob = out + (size_t)b*4194304 + i*256;
  const int sw = (w & 1) << 4;
  #pragma unroll
  for (int c4 = 0; c4 < 4; ++c4) {
    #pragma unroll
    for (int cc = 0; cc < 16; ++cc) {
      const int ch = c4*16 + cc;
      const float4 wa = *reinterpret_cast<const float4*>(wmxw + ch*16 + 8);
      const float4 wb = *reinterpret_cast<const float4*>(wmxw + ch*16 + 12);
      float acc = fea[ch];
      acc += wa.x*m0 + wa.y*m1 + wa.z*m2 + wa.w*m3;
      acc += wb.x*m4 + wb.y*m5 + wb.z*m6 + wb.w*m7;
      tile[cc*256 + w*64 + (l ^ sw)] = acc;   // value for j = 4*l + w
    }
    __syncthreads();
    #pragma unroll
    for (int cc = 0; cc < 16; ++cc) {
      const int ch = c4*16 + cc;
      // thread (w,l) stores j = w*64 + l  <-  slot (w_src=l&3, l_src=w*16+(l>>2))
      const float v = tile[cc*256 + (l&3)*64 + ((w*16 + (l>>2)) ^ ((l&1)<<4))];
      ob[ch*65536 + w*64 + l] = v;
    }
    __syncthreads();
  }
}

extern "C" void kernel_launch(void* const* d_in, const int* in_sizes, int n_in,
                              void* d_out, int out_size, void* d_ws, size_t ws_size,
                              hipStream_t stream) {
  const float* x   = (const float*)d_in[0];
  const float* wc  = (const float*)d_in[1];
  const float* we  = (const float*)d_in[2];
  const float* Wb1 = (const float*)d_in[3];
  const float* bb1 = (const float*)d_in[4];
  const float* Wb2 = (const float*)d_in[5];
  const float* bb2 = (const float*)d_in[6];
  const float* Wr1 = (const float*)d_in[7];
  const float* br1 = (const float*)d_in[8];
  const float* Wr2 = (const float*)d_in[9];
  const float* br2 = (const float*)d_in[10];
  const float* Wq1 = (const float*)d_in[11];
  const float* bq1 = (const float*)d_in[12];
  const float* Wq2 = (const float*)d_in[13];
  const float* bq2 = (const float*)d_in[14];
  const float* Wq3 = (const float*)d_in[15];
  const float* bq3 = (const float*)d_in[16];
  const float* Wo1 = (const float*)d_in[17];
  const float* bo1 = (const float*)d_in[18];
  const float* Wo2 = (const float*)d_in[19];
  const float* bo2 = (const float*)d_in[20];
  const float* Wo3 = (const float*)d_in[21];
  const float* bo3 = (const float*)d_in[22];
  float* ws  = (float*)d_ws;
  float* out = (float*)d_out;

  k_mean<<<dim3(64, 4), 256, 0, stream>>>(x, ws);
  k_phase<<<16, 256, 0, stream>>>(wc, we, Wb1, bb1, Wb2, bb2, Wr1, br1, Wr2, br2,
                                  Wq1, bq1, Wq2, bq2, Wq3, bq3,
                                  Wo1, bo1, Wo2, bo2, Wo3, bo3, ws);
  k_main<<<dim3(256, 4), 256, 0, stream>>>(ws, out);
}